// Round 2
// baseline (669.746 us; speedup 1.0000x reference)
//
#include <hip/hip_runtime.h>
#include <hip/hip_bf16.h>

#define NN 50000
#define NE 800000
#define HH 128

typedef short s16x8 __attribute__((ext_vector_type(8)));
typedef float f32x4 __attribute__((ext_vector_type(4)));

__device__ __forceinline__ unsigned short f2bf(float f) {
    unsigned int x;
    __builtin_memcpy(&x, &f, 4);
    unsigned int r = (x + 0x7fffu + ((x >> 16) & 1u)) >> 16;
    return (unsigned short)r;
}
__device__ __forceinline__ float silu(float v) { return v / (1.f + __expf(-v)); }

// ---- weight transpose+cast: W[k][128] f32 -> WT[n][K] bf16 ----
__global__ void transpose_w(const float* __restrict__ W,
                            unsigned short* __restrict__ WT, int K) {
    int idx = blockIdx.x * 256 + threadIdx.x;
    if (idx >= 128 * K) return;
    int n = idx / K, k = idx - n * K;
    WT[idx] = f2bf(W[k * 128 + n]);
}

// ---- edge kernel: 64 edges per block, 4 waves ----
__global__ __launch_bounds__(256, 2) void edge_kernel(
    const float* __restrict__ h, const float* __restrict__ x,
    const int* __restrict__ eidx,
    const unsigned short* __restrict__ W1T, const float* __restrict__ b1,
    const float* __restrict__ W1full,  // [257][128] f32, row 256 = radial row
    const unsigned short* __restrict__ W2T, const float* __restrict__ b2,
    const unsigned short* __restrict__ Wc1T, const float* __restrict__ bc1,
    const float* __restrict__ wc2,
    float* __restrict__ m_i, float* __restrict__ x_acc) {
    __shared__ unsigned short Alds[64 * 264];   // [64 edges][256 + 8 pad] bf16
    __shared__ unsigned short mid1[64 * 136];   // [64][128 + 8 pad]
    __shared__ unsigned short mid2[64 * 136];
    __shared__ float rad[64], ndx[64], ndy[64], ndz[64], fsum[64];
    __shared__ int rowA[64], colA[64];

    const int tid = threadIdx.x;
    const int e0 = blockIdx.x * 64;

    if (tid < 64) {
        int r = eidx[e0 + tid];
        int c = eidx[NE + e0 + tid];
        r = r < 0 ? 0 : (r >= NN ? NN - 1 : r);
        c = c < 0 ? 0 : (c >= NN ? NN - 1 : c);
        rowA[tid] = r; colA[tid] = c;
        float dx = x[r * 3 + 0] - x[c * 3 + 0];
        float dy = x[r * 3 + 1] - x[c * 3 + 1];
        float dz = x[r * 3 + 2] - x[c * 3 + 2];
        float d2 = dx * dx + dy * dy + dz * dz;
        float dist = sqrtf(d2);
        float inv = 1.f / (dist + 1e-8f);
        rad[tid] = d2;
        ndx[tid] = dx * inv; ndy[tid] = dy * inv; ndz[tid] = dz * inv;
        fsum[tid] = 0.f;
    }
    __syncthreads();

    // stage A = [h[row] | h[col]] f32 -> bf16 : 128 half-rows x 16 chunks of 8
#pragma unroll
    for (int i = 0; i < 8; i++) {
        int idx = tid + i * 256;
        int hr = idx >> 4, ch = idx & 15;
        int e = hr >> 1, half = hr & 1;
        int node = half ? colA[e] : rowA[e];
        const f32x4* hp = (const f32x4*)&h[node * 128 + ch * 8];
        f32x4 f0 = hp[0], f1 = hp[1];
        s16x8 s;
#pragma unroll
        for (int j = 0; j < 4; j++) {
            s[j] = (short)f2bf(f0[j]);
            s[j + 4] = (short)f2bf(f1[j]);
        }
        *(s16x8*)&Alds[e * 264 + half * 128 + ch * 8] = s;
    }
    __syncthreads();

    const int lane = tid & 63;
    const int w = tid >> 6;
    const int ln15 = lane & 15;
    const int q8 = (lane >> 4) * 8, q4 = (lane >> 4) * 4;
    const int nbase = w * 32;  // this wave's output-column base

    f32x4 acc[4][2];

    // ---- layer e1: [64x256] @ W1 -> [64x128], + bias + radial*W1[256], silu
#pragma unroll
    for (int et = 0; et < 4; et++)
#pragma unroll
        for (int nt = 0; nt < 2; nt++) acc[et][nt] = (f32x4){0.f, 0.f, 0.f, 0.f};
#pragma unroll
    for (int kk = 0; kk < 8; kk++) {
        int k0 = kk * 32 + q8;
        s16x8 a[4], b[2];
#pragma unroll
        for (int et = 0; et < 4; et++)
            a[et] = *(const s16x8*)&Alds[(et * 16 + ln15) * 264 + k0];
#pragma unroll
        for (int nt = 0; nt < 2; nt++)
            b[nt] = *(const s16x8*)&W1T[(nbase + nt * 16 + ln15) * 256 + k0];
#pragma unroll
        for (int et = 0; et < 4; et++)
#pragma unroll
            for (int nt = 0; nt < 2; nt++)
                acc[et][nt] = __builtin_amdgcn_mfma_f32_16x16x32_bf16(
                    a[et], b[nt], acc[et][nt], 0, 0, 0);
    }
#pragma unroll
    for (int nt = 0; nt < 2; nt++) {
        int col = nbase + nt * 16 + ln15;
        float bias = b1[col];
        float wlast = W1full[256 * 128 + col];
#pragma unroll
        for (int et = 0; et < 4; et++)
#pragma unroll
            for (int r = 0; r < 4; r++) {
                int row = et * 16 + q4 + r;
                float v = acc[et][nt][r] + bias + rad[row] * wlast;
                mid1[row * 136 + col] = f2bf(silu(v));
            }
    }
    __syncthreads();

    // ---- layer e2: [64x128] @ W2 -> m_ij, silu; scatter to m_i; stash in mid2
#pragma unroll
    for (int et = 0; et < 4; et++)
#pragma unroll
        for (int nt = 0; nt < 2; nt++) acc[et][nt] = (f32x4){0.f, 0.f, 0.f, 0.f};
#pragma unroll
    for (int kk = 0; kk < 4; kk++) {
        int k0 = kk * 32 + q8;
        s16x8 a[4], b[2];
#pragma unroll
        for (int et = 0; et < 4; et++)
            a[et] = *(const s16x8*)&mid1[(et * 16 + ln15) * 136 + k0];
#pragma unroll
        for (int nt = 0; nt < 2; nt++)
            b[nt] = *(const s16x8*)&W2T[(nbase + nt * 16 + ln15) * 128 + k0];
#pragma unroll
        for (int et = 0; et < 4; et++)
#pragma unroll
            for (int nt = 0; nt < 2; nt++)
                acc[et][nt] = __builtin_amdgcn_mfma_f32_16x16x32_bf16(
                    a[et], b[nt], acc[et][nt], 0, 0, 0);
    }
#pragma unroll
    for (int nt = 0; nt < 2; nt++) {
        int col = nbase + nt * 16 + ln15;
        float bias = b2[col];
#pragma unroll
        for (int et = 0; et < 4; et++)
#pragma unroll
            for (int r = 0; r < 4; r++) {
                int row = et * 16 + q4 + r;
                float v = silu(acc[et][nt][r] + bias);
                atomicAdd(&m_i[rowA[row] * 128 + col], v);
                mid2[row * 136 + col] = f2bf(v);
            }
    }
    __syncthreads();

    // ---- coord layer: c1 = silu(m_ij @ Wc1 + bc1); fs = tanh(c1 . wc2)*0.1
#pragma unroll
    for (int et = 0; et < 4; et++)
#pragma unroll
        for (int nt = 0; nt < 2; nt++) acc[et][nt] = (f32x4){0.f, 0.f, 0.f, 0.f};
#pragma unroll
    for (int kk = 0; kk < 4; kk++) {
        int k0 = kk * 32 + q8;
        s16x8 a[4], b[2];
#pragma unroll
        for (int et = 0; et < 4; et++)
            a[et] = *(const s16x8*)&mid2[(et * 16 + ln15) * 136 + k0];
#pragma unroll
        for (int nt = 0; nt < 2; nt++)
            b[nt] = *(const s16x8*)&Wc1T[(nbase + nt * 16 + ln15) * 128 + k0];
#pragma unroll
        for (int et = 0; et < 4; et++)
#pragma unroll
            for (int nt = 0; nt < 2; nt++)
                acc[et][nt] = __builtin_amdgcn_mfma_f32_16x16x32_bf16(
                    a[et], b[nt], acc[et][nt], 0, 0, 0);
    }
    {
        float part[4][4];
#pragma unroll
        for (int et = 0; et < 4; et++)
#pragma unroll
            for (int r = 0; r < 4; r++) part[et][r] = 0.f;
#pragma unroll
        for (int nt = 0; nt < 2; nt++) {
            int col = nbase + nt * 16 + ln15;
            float bias = bc1[col];
            float w2 = wc2[col];
#pragma unroll
            for (int et = 0; et < 4; et++)
#pragma unroll
                for (int r = 0; r < 4; r++)
                    part[et][r] += silu(acc[et][nt][r] + bias) * w2;
        }
#pragma unroll
        for (int et = 0; et < 4; et++)
#pragma unroll
            for (int r = 0; r < 4; r++) {
                float p = part[et][r];
                p += __shfl_xor(p, 8, 16);
                p += __shfl_xor(p, 4, 16);
                p += __shfl_xor(p, 2, 16);
                p += __shfl_xor(p, 1, 16);
                if (ln15 == 0) atomicAdd(&fsum[et * 16 + q4 + r], p);
            }
    }
    __syncthreads();
    if (tid < 64) {
        float fs = tanhf(fsum[tid]) * 0.1f;
        int rn = rowA[tid];
        atomicAdd(&x_acc[rn * 3 + 0], ndx[tid] * fs);
        atomicAdd(&x_acc[rn * 3 + 1], ndy[tid] * fs);
        atomicAdd(&x_acc[rn * 3 + 2], ndz[tid] * fs);
    }
}

// ---- node kernel: 64 nodes per block ----
__global__ __launch_bounds__(256, 2) void node_kernel(
    const float* __restrict__ h, const float* __restrict__ m_i,
    const unsigned short* __restrict__ Wn1T, const float* __restrict__ bn1,
    const unsigned short* __restrict__ Wn2T, const float* __restrict__ bn2,
    const float* __restrict__ ln_g, const float* __restrict__ ln_b,
    float* __restrict__ out_h) {
    __shared__ unsigned short Alds[64 * 264];
    __shared__ unsigned short mid1[64 * 136];

    const int tid = threadIdx.x;
    const int n0 = blockIdx.x * 64;

    // stage A = [bf16(h) | bf16(m_i)]
#pragma unroll
    for (int i = 0; i < 8; i++) {
        int idx = tid + i * 256;
        int hr = idx >> 4, ch = idx & 15;
        int e = hr >> 1, half = hr & 1;
        int node = n0 + e;
        if (node >= NN) node = NN - 1;
        const float* src = half ? &m_i[node * 128 + ch * 8] : &h[node * 128 + ch * 8];
        const f32x4* sp = (const f32x4*)src;
        f32x4 f0 = sp[0], f1 = sp[1];
        s16x8 s;
#pragma unroll
        for (int j = 0; j < 4; j++) {
            s[j] = (short)f2bf(f0[j]);
            s[j + 4] = (short)f2bf(f1[j]);
        }
        *(s16x8*)&Alds[e * 264 + half * 128 + ch * 8] = s;
    }
    __syncthreads();

    const int lane = tid & 63;
    const int w = tid >> 6;
    const int ln15 = lane & 15;
    const int q8 = (lane >> 4) * 8, q4 = (lane >> 4) * 4;
    const int nbase = w * 32;

    f32x4 acc[4][2];

    // ---- layer n1: K=256
#pragma unroll
    for (int et = 0; et < 4; et++)
#pragma unroll
        for (int nt = 0; nt < 2; nt++) acc[et][nt] = (f32x4){0.f, 0.f, 0.f, 0.f};
#pragma unroll
    for (int kk = 0; kk < 8; kk++) {
        int k0 = kk * 32 + q8;
        s16x8 a[4], b[2];
#pragma unroll
        for (int et = 0; et < 4; et++)
            a[et] = *(const s16x8*)&Alds[(et * 16 + ln15) * 264 + k0];
#pragma unroll
        for (int nt = 0; nt < 2; nt++)
            b[nt] = *(const s16x8*)&Wn1T[(nbase + nt * 16 + ln15) * 256 + k0];
#pragma unroll
        for (int et = 0; et < 4; et++)
#pragma unroll
            for (int nt = 0; nt < 2; nt++)
                acc[et][nt] = __builtin_amdgcn_mfma_f32_16x16x32_bf16(
                    a[et], b[nt], acc[et][nt], 0, 0, 0);
    }
#pragma unroll
    for (int nt = 0; nt < 2; nt++) {
        int col = nbase + nt * 16 + ln15;
        float bias = bn1[col];
#pragma unroll
        for (int et = 0; et < 4; et++)
#pragma unroll
            for (int r = 0; r < 4; r++) {
                int row = et * 16 + q4 + r;
                mid1[row * 136 + col] = f2bf(silu(acc[et][nt][r] + bias));
            }
    }
    __syncthreads();

    // ---- layer n2: K=128, epilogue residual + stash f32 in tile
#pragma unroll
    for (int et = 0; et < 4; et++)
#pragma unroll
        for (int nt = 0; nt < 2; nt++) acc[et][nt] = (f32x4){0.f, 0.f, 0.f, 0.f};
#pragma unroll
    for (int kk = 0; kk < 4; kk++) {
        int k0 = kk * 32 + q8;
        s16x8 a[4], b[2];
#pragma unroll
        for (int et = 0; et < 4; et++)
            a[et] = *(const s16x8*)&mid1[(et * 16 + ln15) * 136 + k0];
#pragma unroll
        for (int nt = 0; nt < 2; nt++)
            b[nt] = *(const s16x8*)&Wn2T[(nbase + nt * 16 + ln15) * 128 + k0];
#pragma unroll
        for (int et = 0; et < 4; et++)
#pragma unroll
            for (int nt = 0; nt < 2; nt++)
                acc[et][nt] = __builtin_amdgcn_mfma_f32_16x16x32_bf16(
                    a[et], b[nt], acc[et][nt], 0, 0, 0);
    }
    __syncthreads();  // Alds (A staging) no longer needed; reuse as f32 tile
    float* tile = (float*)Alds;  // [64][132] f32 = 33792 B, fits exactly
#pragma unroll
    for (int nt = 0; nt < 2; nt++) {
        int col = nbase + nt * 16 + ln15;
        float bias = bn2[col];
#pragma unroll
        for (int et = 0; et < 4; et++)
#pragma unroll
            for (int r = 0; r < 4; r++) {
                int row = et * 16 + q4 + r;
                int node = n0 + row;
                int nclamp = node >= NN ? NN - 1 : node;
                float v = acc[et][nt][r] + bias + h[nclamp * 128 + col];
                tile[row * 132 + col] = v;
            }
    }
    __syncthreads();

    // ---- LayerNorm: 4 threads per row, 32 cols each
    {
        int row = tid >> 2;
        int c0 = (tid & 3) * 32;
        float s = 0.f, s2 = 0.f;
#pragma unroll
        for (int c = 0; c < 32; c++) {
            float v = tile[row * 132 + c0 + c];
            s += v; s2 += v * v;
        }
        s += __shfl_xor(s, 1, 4);  s2 += __shfl_xor(s2, 1, 4);
        s += __shfl_xor(s, 2, 4);  s2 += __shfl_xor(s2, 2, 4);
        float mean = s * (1.f / 128.f);
        float var = s2 * (1.f / 128.f) - mean * mean;
        float rs = rsqrtf(var + 1e-5f);
        int node = n0 + row;
        if (node < NN) {
#pragma unroll
            for (int c = 0; c < 32; c++) {
                int col = c0 + c;
                float v = (tile[row * 132 + col] - mean) * rs * ln_g[col] + ln_b[col];
                out_h[node * 128 + col] = v;
            }
        }
    }
}

// ---- x update ----
__global__ void x_kernel(const float* __restrict__ x,
                         const float* __restrict__ x_acc,
                         float* __restrict__ out_x) {
    int i = blockIdx.x * 256 + threadIdx.x;
    if (i < NN * 3) out_x[i] = x[i] + x_acc[i];
}

extern "C" void kernel_launch(void* const* d_in, const int* in_sizes, int n_in,
                              void* d_out, int out_size, void* d_ws, size_t ws_size,
                              hipStream_t stream) {
    const float* h    = (const float*)d_in[0];
    const float* x    = (const float*)d_in[1];
    const int* eidx   = (const int*)d_in[2];
    const float* W_e1 = (const float*)d_in[3];
    const float* b_e1 = (const float*)d_in[4];
    const float* W_e2 = (const float*)d_in[5];
    const float* b_e2 = (const float*)d_in[6];
    const float* W_c1 = (const float*)d_in[7];
    const float* b_c1 = (const float*)d_in[8];
    const float* W_c2 = (const float*)d_in[9];
    const float* W_n1 = (const float*)d_in[10];
    const float* b_n1 = (const float*)d_in[11];
    const float* W_n2 = (const float*)d_in[12];
    const float* b_n2 = (const float*)d_in[13];
    const float* ln_g = (const float*)d_in[14];
    const float* ln_b = (const float*)d_in[15];

    float* out_h = (float*)d_out;
    float* out_x = out_h + NN * HH;

    // workspace layout
    float* m_i   = (float*)d_ws;                                  // 25,600,000 B
    float* x_acc = (float*)((char*)d_ws + 25600000);              //    600,000 B
    unsigned short* W1T  = (unsigned short*)((char*)d_ws + 26200000);  // bf16
    unsigned short* W2T  = W1T + 128 * 256;
    unsigned short* Wc1T = W2T + 128 * 128;
    unsigned short* Wn1T = Wc1T + 128 * 128;
    unsigned short* Wn2T = Wn1T + 128 * 256;

    hipMemsetAsync(d_ws, 0, 26200000, stream);
    transpose_w<<<(128 * 256 + 255) / 256, 256, 0, stream>>>(W_e1, W1T, 256);
    transpose_w<<<(128 * 128 + 255) / 256, 256, 0, stream>>>(W_e2, W2T, 128);
    transpose_w<<<(128 * 128 + 255) / 256, 256, 0, stream>>>(W_c1, Wc1T, 128);
    transpose_w<<<(128 * 256 + 255) / 256, 256, 0, stream>>>(W_n1, Wn1T, 256);
    transpose_w<<<(128 * 128 + 255) / 256, 256, 0, stream>>>(W_n2, Wn2T, 128);

    edge_kernel<<<NE / 64, 256, 0, stream>>>(h, x, eidx, W1T, b_e1, W_e1, W2T,
                                             b_e2, Wc1T, b_c1, W_c2, m_i, x_acc);
    node_kernel<<<(NN + 63) / 64, 256, 0, stream>>>(h, m_i, Wn1T, b_n1, Wn2T,
                                                    b_n2, ln_g, ln_b, out_h);
    x_kernel<<<(NN * 3 + 255) / 256, 256, 0, stream>>>(x, x_acc, out_x);
}

// Round 3
// 641.110 us; speedup vs baseline: 1.0447x; 1.0447x over previous
//
#include <hip/hip_runtime.h>
#include <hip/hip_bf16.h>

#define NN 50000
#define NE 800000
#define HH 128
#define SCAN_NB 196  // ceil(50000/256)

typedef short s16x8 __attribute__((ext_vector_type(8)));
typedef float f32x4 __attribute__((ext_vector_type(4)));

__device__ __forceinline__ float bf2f(unsigned short u) {
    unsigned int v = ((unsigned int)u) << 16;
    float f;
    __builtin_memcpy(&f, &v, 4);
    return f;
}
__device__ __forceinline__ unsigned short f2bf(float f) {
    unsigned int x;
    __builtin_memcpy(&x, &f, 4);
    unsigned int r = (x + 0x7fffu + ((x >> 16) & 1u)) >> 16;
    return (unsigned short)r;
}
__device__ __forceinline__ float silu(float v) { return v / (1.f + __expf(-v)); }

// ---- weight transpose+cast: W[k][128] f32 -> WT[n][K] bf16 ----
__global__ void transpose_w(const float* __restrict__ W,
                            unsigned short* __restrict__ WT, int K) {
    int idx = blockIdx.x * 256 + threadIdx.x;
    if (idx >= 128 * K) return;
    int n = idx / K, k = idx - n * K;
    WT[idx] = f2bf(W[k * 128 + n]);
}

// ---- CSR build ----
__global__ void k_count(const int* __restrict__ eidx, int* __restrict__ counts) {
    int e = blockIdx.x * 256 + threadIdx.x;
    if (e >= NE) return;
    int r = eidx[e];
    r = r < 0 ? 0 : (r >= NN ? NN - 1 : r);
    atomicAdd(&counts[r], 1);
}
__global__ void k_partial(const int* __restrict__ counts, int* __restrict__ partials) {
    __shared__ int sm[256];
    int idx = blockIdx.x * 256 + threadIdx.x;
    sm[threadIdx.x] = idx < NN ? counts[idx] : 0;
    __syncthreads();
    for (int s = 128; s > 0; s >>= 1) {
        if (threadIdx.x < s) sm[threadIdx.x] += sm[threadIdx.x + s];
        __syncthreads();
    }
    if (threadIdx.x == 0) partials[blockIdx.x] = sm[0];
}
__global__ void k_scanp(const int* __restrict__ partials, int* __restrict__ scanp) {
    __shared__ int sm[256];
    int t = threadIdx.x;
    int v = t < SCAN_NB ? partials[t] : 0;
    sm[t] = v;
    __syncthreads();
    for (int d = 1; d < 256; d <<= 1) {
        int add = t >= d ? sm[t - d] : 0;
        __syncthreads();
        sm[t] += add;
        __syncthreads();
    }
    scanp[t] = sm[t] - v;  // exclusive
}
__global__ void k_offsets(const int* __restrict__ counts, const int* __restrict__ scanp,
                          int* __restrict__ offsets) {
    __shared__ int sm[256];
    int t = threadIdx.x, idx = blockIdx.x * 256 + t;
    int v = idx < NN ? counts[idx] : 0;
    sm[t] = v;
    __syncthreads();
    for (int d = 1; d < 256; d <<= 1) {
        int add = t >= d ? sm[t - d] : 0;
        __syncthreads();
        sm[t] += add;
        __syncthreads();
    }
    if (idx < NN) offsets[idx] = sm[t] - v + scanp[blockIdx.x];
}
__global__ void k_fill(const int* __restrict__ eidx, const int* __restrict__ offsets,
                       int* __restrict__ cursor, int* __restrict__ perm) {
    int e = blockIdx.x * 256 + threadIdx.x;
    if (e >= NE) return;
    int r = eidx[e];
    r = r < 0 ? 0 : (r >= NN ? NN - 1 : r);
    int slot = offsets[r] + atomicAdd(&cursor[r], 1);
    perm[slot] = e;
}

// ---- edge kernel: 64 edges per block, 4 waves ----
// BIG: write m_ij bf16 to mixbuf (no m_i atomics). !BIG: atomicAdd into m_i.
template <bool BIG>
__global__ __launch_bounds__(256, 3) void edge_kernel(
    const float* __restrict__ h, const float* __restrict__ x,
    const int* __restrict__ eidx,
    const unsigned short* __restrict__ W1T, const float* __restrict__ b1,
    const float* __restrict__ W1full,  // [257][128] f32, row 256 = radial row
    const unsigned short* __restrict__ W2T, const float* __restrict__ b2,
    const unsigned short* __restrict__ Wc1T, const float* __restrict__ bc1,
    const float* __restrict__ wc2,
    float* __restrict__ m_i, unsigned short* __restrict__ mixbuf,
    float* __restrict__ x_acc) {
    __shared__ unsigned short Alds[64 * 264];  // [64 edges][256+8] bf16 (A for e1)
    __shared__ unsigned short mid1[64 * 136];  // [64][128+8]
    unsigned short* mid2 = Alds;               // alias: A dead after e1 k-loop
    __shared__ float rad[64], ndx[64], ndy[64], ndz[64], fsum[64];
    __shared__ int rowA[64], colA[64];

    const int tid = threadIdx.x;
    const int e0 = blockIdx.x * 64;

    if (tid < 64) {
        int r = eidx[e0 + tid];
        int c = eidx[NE + e0 + tid];
        r = r < 0 ? 0 : (r >= NN ? NN - 1 : r);
        c = c < 0 ? 0 : (c >= NN ? NN - 1 : c);
        rowA[tid] = r; colA[tid] = c;
        float dx = x[r * 3 + 0] - x[c * 3 + 0];
        float dy = x[r * 3 + 1] - x[c * 3 + 1];
        float dz = x[r * 3 + 2] - x[c * 3 + 2];
        float d2 = dx * dx + dy * dy + dz * dz;
        float dist = sqrtf(d2);
        float inv = 1.f / (dist + 1e-8f);
        rad[tid] = d2;
        ndx[tid] = dx * inv; ndy[tid] = dy * inv; ndz[tid] = dz * inv;
        fsum[tid] = 0.f;
    }
    __syncthreads();

    // stage A = [h[row] | h[col]] f32 -> bf16
#pragma unroll
    for (int i = 0; i < 8; i++) {
        int idx = tid + i * 256;
        int hr = idx >> 4, ch = idx & 15;
        int e = hr >> 1, half = hr & 1;
        int node = half ? colA[e] : rowA[e];
        const f32x4* hp = (const f32x4*)&h[node * 128 + ch * 8];
        f32x4 f0 = hp[0], f1 = hp[1];
        s16x8 s;
#pragma unroll
        for (int j = 0; j < 4; j++) {
            s[j] = (short)f2bf(f0[j]);
            s[j + 4] = (short)f2bf(f1[j]);
        }
        *(s16x8*)&Alds[e * 264 + half * 128 + ch * 8] = s;
    }
    __syncthreads();

    const int lane = tid & 63;
    const int w = tid >> 6;
    const int ln15 = lane & 15;
    const int q8 = (lane >> 4) * 8, q4 = (lane >> 4) * 4;
    const int nbase = w * 32;

    f32x4 acc[4][2];

    // ---- layer e1: [64x256]@W1 + bias + radial*W1[256], silu -> mid1
#pragma unroll
    for (int et = 0; et < 4; et++)
#pragma unroll
        for (int nt = 0; nt < 2; nt++) acc[et][nt] = (f32x4){0.f, 0.f, 0.f, 0.f};
#pragma unroll
    for (int kk = 0; kk < 8; kk++) {
        int k0 = kk * 32 + q8;
        s16x8 a[4], b[2];
#pragma unroll
        for (int et = 0; et < 4; et++)
            a[et] = *(const s16x8*)&Alds[(et * 16 + ln15) * 264 + k0];
#pragma unroll
        for (int nt = 0; nt < 2; nt++)
            b[nt] = *(const s16x8*)&W1T[(nbase + nt * 16 + ln15) * 256 + k0];
#pragma unroll
        for (int et = 0; et < 4; et++)
#pragma unroll
            for (int nt = 0; nt < 2; nt++)
                acc[et][nt] = __builtin_amdgcn_mfma_f32_16x16x32_bf16(
                    a[et], b[nt], acc[et][nt], 0, 0, 0);
    }
#pragma unroll
    for (int nt = 0; nt < 2; nt++) {
        int col = nbase + nt * 16 + ln15;
        float bias = b1[col];
        float wlast = W1full[256 * 128 + col];
#pragma unroll
        for (int et = 0; et < 4; et++)
#pragma unroll
            for (int r = 0; r < 4; r++) {
                int row = et * 16 + q4 + r;
                float v = acc[et][nt][r] + bias + rad[row] * wlast;
                mid1[row * 136 + col] = f2bf(silu(v));
            }
    }
    __syncthreads();

    // ---- layer e2: silu([64x128]@W2 + b2) = m_ij -> mid2 (+ atomics if !BIG)
#pragma unroll
    for (int et = 0; et < 4; et++)
#pragma unroll
        for (int nt = 0; nt < 2; nt++) acc[et][nt] = (f32x4){0.f, 0.f, 0.f, 0.f};
#pragma unroll
    for (int kk = 0; kk < 4; kk++) {
        int k0 = kk * 32 + q8;
        s16x8 a[4], b[2];
#pragma unroll
        for (int et = 0; et < 4; et++)
            a[et] = *(const s16x8*)&mid1[(et * 16 + ln15) * 136 + k0];
#pragma unroll
        for (int nt = 0; nt < 2; nt++)
            b[nt] = *(const s16x8*)&W2T[(nbase + nt * 16 + ln15) * 128 + k0];
#pragma unroll
        for (int et = 0; et < 4; et++)
#pragma unroll
            for (int nt = 0; nt < 2; nt++)
                acc[et][nt] = __builtin_amdgcn_mfma_f32_16x16x32_bf16(
                    a[et], b[nt], acc[et][nt], 0, 0, 0);
    }
#pragma unroll
    for (int nt = 0; nt < 2; nt++) {
        int col = nbase + nt * 16 + ln15;
        float bias = b2[col];
#pragma unroll
        for (int et = 0; et < 4; et++)
#pragma unroll
            for (int r = 0; r < 4; r++) {
                int row = et * 16 + q4 + r;
                float v = silu(acc[et][nt][r] + bias);
                if (!BIG) atomicAdd(&m_i[rowA[row] * 128 + col], v);
                mid2[row * 136 + col] = f2bf(v);
            }
    }
    __syncthreads();

    // ---- coord layer: c1 = silu(m_ij @ Wc1 + bc1); fs = tanh(c1.wc2)*0.1
#pragma unroll
    for (int et = 0; et < 4; et++)
#pragma unroll
        for (int nt = 0; nt < 2; nt++) acc[et][nt] = (f32x4){0.f, 0.f, 0.f, 0.f};
#pragma unroll
    for (int kk = 0; kk < 4; kk++) {
        int k0 = kk * 32 + q8;
        s16x8 a[4], b[2];
#pragma unroll
        for (int et = 0; et < 4; et++)
            a[et] = *(const s16x8*)&mid2[(et * 16 + ln15) * 136 + k0];
#pragma unroll
        for (int nt = 0; nt < 2; nt++)
            b[nt] = *(const s16x8*)&Wc1T[(nbase + nt * 16 + ln15) * 128 + k0];
#pragma unroll
        for (int et = 0; et < 4; et++)
#pragma unroll
            for (int nt = 0; nt < 2; nt++)
                acc[et][nt] = __builtin_amdgcn_mfma_f32_16x16x32_bf16(
                    a[et], b[nt], acc[et][nt], 0, 0, 0);
    }

    if (BIG) {  // coalesced m_ij export (mid2 stable since last barrier)
#pragma unroll
        for (int j = 0; j < 4; j++) {
            int c = tid + j * 256;
            int row = c >> 4, ch = c & 15;
            *(s16x8*)&mixbuf[(size_t)(e0 + row) * 128 + ch * 8] =
                *(s16x8*)&mid2[row * 136 + ch * 8];
        }
    }

    {
        float part[4][4];
#pragma unroll
        for (int et = 0; et < 4; et++)
#pragma unroll
            for (int r = 0; r < 4; r++) part[et][r] = 0.f;
#pragma unroll
        for (int nt = 0; nt < 2; nt++) {
            int col = nbase + nt * 16 + ln15;
            float bias = bc1[col];
            float w2 = wc2[col];
#pragma unroll
            for (int et = 0; et < 4; et++)
#pragma unroll
                for (int r = 0; r < 4; r++)
                    part[et][r] += silu(acc[et][nt][r] + bias) * w2;
        }
#pragma unroll
        for (int et = 0; et < 4; et++)
#pragma unroll
            for (int r = 0; r < 4; r++) {
                float p = part[et][r];
                p += __shfl_xor(p, 8, 16);
                p += __shfl_xor(p, 4, 16);
                p += __shfl_xor(p, 2, 16);
                p += __shfl_xor(p, 1, 16);
                if (ln15 == 0) atomicAdd(&fsum[et * 16 + q4 + r], p);
            }
    }
    __syncthreads();
    if (tid < 64) {
        float fs = tanhf(fsum[tid]) * 0.1f;
        int rn = rowA[tid];
        atomicAdd(&x_acc[rn * 3 + 0], ndx[tid] * fs);
        atomicAdd(&x_acc[rn * 3 + 1], ndy[tid] * fs);
        atomicAdd(&x_acc[rn * 3 + 2], ndz[tid] * fs);
    }
}

// ---- node kernel: 64 nodes per block ----
template <bool BIG>
__global__ __launch_bounds__(256, 3) void node_kernel(
    const float* __restrict__ h, const float* __restrict__ m_i,
    const unsigned short* __restrict__ mixbuf, const int* __restrict__ perm,
    const int* __restrict__ offsets, const int* __restrict__ counts,
    const unsigned short* __restrict__ Wn1T, const float* __restrict__ bn1,
    const unsigned short* __restrict__ Wn2T, const float* __restrict__ bn2,
    const float* __restrict__ ln_g, const float* __restrict__ ln_b,
    float* __restrict__ out_h) {
    __shared__ unsigned short Alds[64 * 264];
    __shared__ unsigned short mid1[64 * 136];

    const int tid = threadIdx.x;
    const int n0 = blockIdx.x * 64;

    if (BIG) {
        // CSR gather: 4 threads per node, 32 cols each; f32 accumulate
        int ln = tid >> 2, q = tid & 3;
        int node = n0 + ln;
        if (node >= NN) node = NN - 1;
        float acc32[32];
#pragma unroll
        for (int i = 0; i < 32; i++) acc32[i] = 0.f;
        int beg = offsets[node], cnt = counts[node];
        for (int k = 0; k < cnt; k++) {
            int eid = perm[beg + k];
            const s16x8* p = (const s16x8*)&mixbuf[(size_t)eid * 128 + q * 32];
#pragma unroll
            for (int j = 0; j < 4; j++) {
                s16x8 v = p[j];
#pragma unroll
                for (int t = 0; t < 8; t++)
                    acc32[j * 8 + t] += bf2f((unsigned short)v[t]);
            }
        }
#pragma unroll
        for (int j = 0; j < 4; j++) {
            s16x8 s;
#pragma unroll
            for (int t = 0; t < 8; t++) s[t] = (short)f2bf(acc32[j * 8 + t]);
            *(s16x8*)&Alds[ln * 264 + 128 + q * 32 + j * 8] = s;
        }
        // h half
#pragma unroll
        for (int j = 0; j < 4; j++) {
            const f32x4* hp = (const f32x4*)&h[node * 128 + q * 32 + j * 8];
            f32x4 f0 = hp[0], f1 = hp[1];
            s16x8 s;
#pragma unroll
            for (int t = 0; t < 4; t++) {
                s[t] = (short)f2bf(f0[t]);
                s[t + 4] = (short)f2bf(f1[t]);
            }
            *(s16x8*)&Alds[ln * 264 + q * 32 + j * 8] = s;
        }
    } else {
        // stage A = [bf16(h) | bf16(m_i)]
#pragma unroll
        for (int i = 0; i < 8; i++) {
            int idx = tid + i * 256;
            int hr = idx >> 4, ch = idx & 15;
            int e = hr >> 1, half = hr & 1;
            int node = n0 + e;
            if (node >= NN) node = NN - 1;
            const float* src =
                half ? &m_i[node * 128 + ch * 8] : &h[node * 128 + ch * 8];
            const f32x4* sp = (const f32x4*)src;
            f32x4 f0 = sp[0], f1 = sp[1];
            s16x8 s;
#pragma unroll
            for (int j = 0; j < 4; j++) {
                s[j] = (short)f2bf(f0[j]);
                s[j + 4] = (short)f2bf(f1[j]);
            }
            *(s16x8*)&Alds[e * 264 + half * 128 + ch * 8] = s;
        }
    }
    __syncthreads();

    const int lane = tid & 63;
    const int w = tid >> 6;
    const int ln15 = lane & 15;
    const int q8 = (lane >> 4) * 8, q4 = (lane >> 4) * 4;
    const int nbase = w * 32;

    f32x4 acc[4][2];

    // ---- layer n1: K=256
#pragma unroll
    for (int et = 0; et < 4; et++)
#pragma unroll
        for (int nt = 0; nt < 2; nt++) acc[et][nt] = (f32x4){0.f, 0.f, 0.f, 0.f};
#pragma unroll
    for (int kk = 0; kk < 8; kk++) {
        int k0 = kk * 32 + q8;
        s16x8 a[4], b[2];
#pragma unroll
        for (int et = 0; et < 4; et++)
            a[et] = *(const s16x8*)&Alds[(et * 16 + ln15) * 264 + k0];
#pragma unroll
        for (int nt = 0; nt < 2; nt++)
            b[nt] = *(const s16x8*)&Wn1T[(nbase + nt * 16 + ln15) * 256 + k0];
#pragma unroll
        for (int et = 0; et < 4; et++)
#pragma unroll
            for (int nt = 0; nt < 2; nt++)
                acc[et][nt] = __builtin_amdgcn_mfma_f32_16x16x32_bf16(
                    a[et], b[nt], acc[et][nt], 0, 0, 0);
    }
#pragma unroll
    for (int nt = 0; nt < 2; nt++) {
        int col = nbase + nt * 16 + ln15;
        float bias = bn1[col];
#pragma unroll
        for (int et = 0; et < 4; et++)
#pragma unroll
            for (int r = 0; r < 4; r++) {
                int row = et * 16 + q4 + r;
                mid1[row * 136 + col] = f2bf(silu(acc[et][nt][r] + bias));
            }
    }
    __syncthreads();

    // ---- layer n2: K=128, epilogue residual + stash f32 in tile
#pragma unroll
    for (int et = 0; et < 4; et++)
#pragma unroll
        for (int nt = 0; nt < 2; nt++) acc[et][nt] = (f32x4){0.f, 0.f, 0.f, 0.f};
#pragma unroll
    for (int kk = 0; kk < 4; kk++) {
        int k0 = kk * 32 + q8;
        s16x8 a[4], b[2];
#pragma unroll
        for (int et = 0; et < 4; et++)
            a[et] = *(const s16x8*)&mid1[(et * 16 + ln15) * 136 + k0];
#pragma unroll
        for (int nt = 0; nt < 2; nt++)
            b[nt] = *(const s16x8*)&Wn2T[(nbase + nt * 16 + ln15) * 128 + k0];
#pragma unroll
        for (int et = 0; et < 4; et++)
#pragma unroll
            for (int nt = 0; nt < 2; nt++)
                acc[et][nt] = __builtin_amdgcn_mfma_f32_16x16x32_bf16(
                    a[et], b[nt], acc[et][nt], 0, 0, 0);
    }
    __syncthreads();
    float* tile = (float*)Alds;  // [64][132] f32 = 33792 B, fits exactly
#pragma unroll
    for (int nt = 0; nt < 2; nt++) {
        int col = nbase + nt * 16 + ln15;
        float bias = bn2[col];
#pragma unroll
        for (int et = 0; et < 4; et++)
#pragma unroll
            for (int r = 0; r < 4; r++) {
                int row = et * 16 + q4 + r;
                int node = n0 + row;
                int nclamp = node >= NN ? NN - 1 : node;
                float v = acc[et][nt][r] + bias + h[nclamp * 128 + col];
                tile[row * 132 + col] = v;
            }
    }
    __syncthreads();

    // ---- LayerNorm: 4 threads per row, 32 cols each
    {
        int row = tid >> 2;
        int c0 = (tid & 3) * 32;
        float s = 0.f, s2 = 0.f;
#pragma unroll
        for (int c = 0; c < 32; c++) {
            float v = tile[row * 132 + c0 + c];
            s += v; s2 += v * v;
        }
        s += __shfl_xor(s, 1, 4);  s2 += __shfl_xor(s2, 1, 4);
        s += __shfl_xor(s, 2, 4);  s2 += __shfl_xor(s2, 2, 4);
        float mean = s * (1.f / 128.f);
        float var = s2 * (1.f / 128.f) - mean * mean;
        float rs = rsqrtf(var + 1e-5f);
        int node = n0 + row;
        if (node < NN) {
#pragma unroll
            for (int c = 0; c < 32; c++) {
                int col = c0 + c;
                float v = (tile[row * 132 + col] - mean) * rs * ln_g[col] + ln_b[col];
                out_h[node * 128 + col] = v;
            }
        }
    }
}

// ---- x update ----
__global__ void x_kernel(const float* __restrict__ x,
                         const float* __restrict__ x_acc,
                         float* __restrict__ out_x) {
    int i = blockIdx.x * 256 + threadIdx.x;
    if (i < NN * 3) out_x[i] = x[i] + x_acc[i];
}

extern "C" void kernel_launch(void* const* d_in, const int* in_sizes, int n_in,
                              void* d_out, int out_size, void* d_ws, size_t ws_size,
                              hipStream_t stream) {
    const float* h    = (const float*)d_in[0];
    const float* x    = (const float*)d_in[1];
    const int* eidx   = (const int*)d_in[2];
    const float* W_e1 = (const float*)d_in[3];
    const float* b_e1 = (const float*)d_in[4];
    const float* W_e2 = (const float*)d_in[5];
    const float* b_e2 = (const float*)d_in[6];
    const float* W_c1 = (const float*)d_in[7];
    const float* b_c1 = (const float*)d_in[8];
    const float* W_c2 = (const float*)d_in[9];
    const float* W_n1 = (const float*)d_in[10];
    const float* b_n1 = (const float*)d_in[11];
    const float* W_n2 = (const float*)d_in[12];
    const float* b_n2 = (const float*)d_in[13];
    const float* ln_g = (const float*)d_in[14];
    const float* ln_b = (const float*)d_in[15];

    float* out_h = (float*)d_out;
    float* out_x = out_h + NN * HH;

    const size_t NEEDED = 209500000;
    bool big = ws_size >= NEEDED;
    char* ws = (char*)d_ws;

    if (big) {
        unsigned short* mixbuf = (unsigned short*)ws;          // 204,800,000 B
        float* x_acc  = (float*)(ws + 204800000);              // 600,000 (zero)
        int* counts   = (int*)(ws + 205400000);                // 200,000 (zero)
        int* cursor   = (int*)(ws + 205600000);                // 200,000 (zero)
        int* offsets  = (int*)(ws + 205800000);                // 200,000
        int* partials = (int*)(ws + 206000000);                // 1,024
        int* scanp    = (int*)(ws + 206001024);                // 1,024
        int* perm     = (int*)(ws + 206002048);                // 3,200,000
        unsigned short* W1T  = (unsigned short*)(ws + 209202048);
        unsigned short* W2T  = W1T + 128 * 256;
        unsigned short* Wc1T = W2T + 128 * 128;
        unsigned short* Wn1T = Wc1T + 128 * 128;
        unsigned short* Wn2T = Wn1T + 128 * 256;

        hipMemsetAsync(ws + 204800000, 0, 1000000, stream);
        transpose_w<<<(128 * 256 + 255) / 256, 256, 0, stream>>>(W_e1, W1T, 256);
        transpose_w<<<(128 * 128 + 255) / 256, 256, 0, stream>>>(W_e2, W2T, 128);
        transpose_w<<<(128 * 128 + 255) / 256, 256, 0, stream>>>(W_c1, Wc1T, 128);
        transpose_w<<<(128 * 256 + 255) / 256, 256, 0, stream>>>(W_n1, Wn1T, 256);
        transpose_w<<<(128 * 128 + 255) / 256, 256, 0, stream>>>(W_n2, Wn2T, 128);
        k_count<<<(NE + 255) / 256, 256, 0, stream>>>(eidx, counts);
        k_partial<<<SCAN_NB, 256, 0, stream>>>(counts, partials);
        k_scanp<<<1, 256, 0, stream>>>(partials, scanp);
        k_offsets<<<SCAN_NB, 256, 0, stream>>>(counts, scanp, offsets);
        k_fill<<<(NE + 255) / 256, 256, 0, stream>>>(eidx, offsets, cursor, perm);

        edge_kernel<true><<<NE / 64, 256, 0, stream>>>(
            h, x, eidx, W1T, b_e1, W_e1, W2T, b_e2, Wc1T, b_c1, W_c2,
            nullptr, mixbuf, x_acc);
        node_kernel<true><<<(NN + 63) / 64, 256, 0, stream>>>(
            h, nullptr, mixbuf, perm, offsets, counts, Wn1T, b_n1, Wn2T, b_n2,
            ln_g, ln_b, out_h);
        x_kernel<<<(NN * 3 + 255) / 256, 256, 0, stream>>>(x, x_acc, out_x);
    } else {
        float* m_i   = (float*)ws;                             // 25,600,000 (zero)
        float* x_acc = (float*)(ws + 25600000);                // 600,000 (zero)
        unsigned short* W1T  = (unsigned short*)(ws + 26200000);
        unsigned short* W2T  = W1T + 128 * 256;
        unsigned short* Wc1T = W2T + 128 * 128;
        unsigned short* Wn1T = Wc1T + 128 * 128;
        unsigned short* Wn2T = Wn1T + 128 * 256;

        hipMemsetAsync(ws, 0, 26200000, stream);
        transpose_w<<<(128 * 256 + 255) / 256, 256, 0, stream>>>(W_e1, W1T, 256);
        transpose_w<<<(128 * 128 + 255) / 256, 256, 0, stream>>>(W_e2, W2T, 128);
        transpose_w<<<(128 * 128 + 255) / 256, 256, 0, stream>>>(W_c1, Wc1T, 128);
        transpose_w<<<(128 * 256 + 255) / 256, 256, 0, stream>>>(W_n1, Wn1T, 256);
        transpose_w<<<(128 * 128 + 255) / 256, 256, 0, stream>>>(W_n2, Wn2T, 128);

        edge_kernel<false><<<NE / 64, 256, 0, stream>>>(
            h, x, eidx, W1T, b_e1, W_e1, W2T, b_e2, Wc1T, b_c1, W_c2,
            m_i, nullptr, x_acc);
        node_kernel<false><<<(NN + 63) / 64, 256, 0, stream>>>(
            h, m_i, nullptr, nullptr, nullptr, nullptr, Wn1T, b_n1, Wn2T, b_n2,
            ln_g, ln_b, out_h);
        x_kernel<<<(NN * 3 + 255) / 256, 256, 0, stream>>>(x, x_acc, out_x);
    }
}